// Round 20
// baseline (2000.306 us; speedup 1.0000x reference)
//
#include <hip/hip_runtime.h>
#include <stdint.h>

typedef unsigned short u16;
typedef short bf16x8 __attribute__((ext_vector_type(8)));
typedef float f32x4 __attribute__((ext_vector_type(4)));
typedef int i32x4 __attribute__((ext_vector_type(4)));

#define DEV static __device__ __forceinline__

constexpr int B_ = 512, T_ = 64, IN_ = 256, H_ = 512, V1_ = 101, P_ = 8, G4_ = 2048;
constexpr int EXR = 613;      // 101 embed rows + 512 x rows
constexpr int M_  = T_ * B_;  // 32768
constexpr int NBLK = 256;     // scan grid: 32 bm x 8 bj; bj == XCD (round-robin %8)

DEV float b2f(u16 u) { union { uint32_t i; float f; } v; v.i = ((uint32_t)u) << 16; return v.f; }
DEV u16 f2b(float f) {
  union { float f; uint32_t i; } v; v.f = f;
  uint32_t i = v.i;
  return (u16)((i + 0x7fffu + ((i >> 16) & 1u)) >> 16);  // RNE
}
DEV float sigf(float x) { return 1.f / (1.f + __expf(-x)); }
DEV float tanh_(float x) {
  float c = fminf(fmaxf(x, -15.f), 15.f);
  float e = __expf(2.f * c);
  return (e - 1.f) / (e + 1.f);
}
DEV bf16x8 ld8(const u16* p) { return *reinterpret_cast<const bf16x8*>(p); }
DEV f32x4 mfma16(bf16x8 a, bf16x8 b, f32x4 c) {
  return __builtin_amdgcn_mfma_f32_16x16x32_bf16(a, b, c, 0, 0, 0);
}

// ---------------- fused f32 -> bf16 conversion over 9 segments ----------------
struct CvtArgs {
  const float* src[9];
  u16* dst[9];
  int pre[10];  // prefix sums in float4 units
};

__global__ __launch_bounds__(256) void k_cvtall(CvtArgs a) {
  int gid = blockIdx.x * 256 + threadIdx.x;
  if (gid >= a.pre[9]) return;
  int s = 0;
#pragma unroll
  for (int i = 1; i < 9; ++i) s += (gid >= a.pre[i]);
  const int local = gid - a.pre[s];
  const float4 v = reinterpret_cast<const float4*>(a.src[s])[local];
  ushort4 o;
  o.x = f2b(v.x); o.y = f2b(v.y); o.z = f2b(v.z); o.w = f2b(v.w);
  reinterpret_cast<ushort4*>(a.dst[s])[local] = o;
}

// ---------------- EX0 = [embed; x] @ w_ih0^T   (613 x 2048) f32 ----------------
__global__ __launch_bounds__(256) void k_precomp(const u16* __restrict__ ex_src,
                                                 const u16* __restrict__ wih0b,
                                                 float* __restrict__ EX0) {
  const int lane = threadIdx.x & 63;
  const int wv = threadIdx.x >> 6;
  const int m0 = blockIdx.x * 64 + wv * 16;
  const int n0 = blockIdx.y * 64;
  const int lr = lane & 15;
  const int lk = (lane >> 4) * 8;

  const int arow = m0 + lr;
  const bool valid = arow < EXR;

  f32x4 acc[4] = {};
  for (int k0 = 0; k0 < IN_; k0 += 32) {
    bf16x8 a = {};
    if (valid) a = ld8(ex_src + (size_t)arow * IN_ + k0 + lk);
#pragma unroll
    for (int c = 0; c < 4; ++c) {
      bf16x8 b = ld8(wih0b + (size_t)(n0 + c * 16 + lr) * IN_ + k0 + lk);
      acc[c] = mfma16(a, b, acc[c]);
    }
  }
  const int rb = (lane >> 4) * 4;
#pragma unroll
  for (int c = 0; c < 4; ++c)
#pragma unroll
    for (int r = 0; r < 4; ++r) {
      int row = m0 + rb + r;
      int col = n0 + c * 16 + (lane & 15);
      if (row < EXR) EX0[(size_t)row * G4_ + col] = acc[c][r];
    }
}

// ---------------- persistent 2-layer LSTM scan (r18 champion, byte-identical) ----------------
__global__ __launch_bounds__(512, 1) void k_scan(
    const u16* __restrict__ whh0, const u16* __restrict__ wih1, const u16* __restrict__ whh1,
    const float* __restrict__ EX0, const int* __restrict__ y,
    u16* h0buf, u16* h1buf, unsigned* flags /* [32][16] u32, pre-zeroed */) {
  __shared__ u16 h0s[16 * 512];   // swizzled
  __shared__ u16 h1s[16 * 512];   // swizzled (L1 only)
  __shared__ u16 stage0[16][64];
  __shared__ u16 stage1[16][64];
  const size_t BH = (size_t)B_ * H_;
  const int tid = threadIdx.x;
  const int lane = tid & 63;
  const int wv = tid >> 6;           // 0..3: layer0 quarter; 4..7: layer1 quarter
  const int q = wv & 3;              // col quarter
  const bool isL1 = wv >= 4;
  const int bm = blockIdx.x >> 3;    // 0..31 batch tile (16 rows)
  const int bj = blockIdx.x & 7;     // 0..7 h-col tile (64 cols) == XCD
  const int lr = lane & 15;
  const int lk = (lane >> 4) * 8;    // k-offset within 32-wide K step
  const int col = bj * 64 + q * 16 + lr;
  const int rb = (lane >> 4) * 4;
  const int lcol = q * 16 + lr;

  const u16* wp[8];  // L0: wp[g]=whh0 ; L1: wp[g]=wih1, wp[4+g]=whh1
#pragma unroll
  for (int g = 0; g < 4; ++g) {
    if (!isL1) {
      wp[g] = whh0 + (size_t)(g * H_ + col) * H_ + lk;
      wp[4 + g] = whh0 + (size_t)(g * H_ + col) * H_ + lk;  // unused, keep defined
    } else {
      wp[g] = wih1 + (size_t)(g * H_ + col) * H_ + lk;
      wp[4 + g] = whh1 + (size_t)(g * H_ + col) * H_ + lk;
    }
  }
  f32x4 cst = {};  // c0 for L0 waves, c1 for L1 waves
  unsigned* gflags = flags + bm * 16;

  for (int k = 0; k <= T_; ++k) {
    // ---- Phase A: cooperative staging of h tiles into swizzled LDS ----
    {
      const u16* h0g = h0buf + (size_t)k * BH + (size_t)(bm * 16) * H_;
#pragma unroll
      for (int rr = 0; rr < 2; ++rr) {
        const int idx = rr * 512 + tid;          // 1024 chunks of 16B
        const int row = idx >> 6, cc = idx & 63;
        i32x4 d = *(const i32x4*)(h0g + (size_t)row * H_ + cc * 8);
        *(i32x4*)((char*)h0s + row * 1024 + ((cc * 16) ^ ((row & 7) << 4))) = d;
      }
      if (k >= 1) {
        const u16* h1g = h1buf + (size_t)(k - 1) * BH + (size_t)(bm * 16) * H_;
#pragma unroll
        for (int rr = 0; rr < 2; ++rr) {
          const int idx = rr * 512 + tid;
          const int row = idx >> 6, cc = idx & 63;
          i32x4 d = *(const i32x4*)(h1g + (size_t)row * H_ + cc * 8);
          *(i32x4*)((char*)h1s + row * 1024 + ((cc * 16) ^ ((row & 7) << 4))) = d;
        }
      }
    }
    __syncthreads();

    // ---- Phase B: compute (depth-3 rolling weight prefetch) ----
    if (!isL1) {
      if (k < T_) {  // layer 0, step k
        float ex[4][4];
#pragma unroll
        for (int r = 0; r < 4; ++r) {
          const int row = bm * 16 + rb + r;
          const int srow = (k == 0) ? (V1_ + row) : y[row * T_ + k - 1];
          const float* bp = EX0 + (size_t)srow * G4_ + col;
#pragma unroll
          for (int g = 0; g < 4; ++g) ex[g][r] = bp[(size_t)g * H_];
        }
        bf16x8 wf0[4], wf1[4], wf2[4];
#pragma unroll
        for (int g = 0; g < 4; ++g) {
          wf0[g] = ld8(wp[g]);
          wf1[g] = ld8(wp[g] + 32);
          wf2[g] = ld8(wp[g] + 64);
        }
        f32x4 acc[4] = {};
#pragma unroll
        for (int i = 0; i < 16; ++i) {
          bf16x8 a0 = *(const bf16x8*)((const char*)h0s + lr * 1024 + (((i * 32 + lk) * 2) ^ ((lr & 7) << 4)));
          bf16x8 cur[4];
#pragma unroll
          for (int g = 0; g < 4; ++g)
            cur[g] = (i % 3 == 0) ? wf0[g] : (i % 3 == 1) ? wf1[g] : wf2[g];
          if (i + 3 < 16) {
#pragma unroll
            for (int g = 0; g < 4; ++g) {
              bf16x8 nv = ld8(wp[g] + (i + 3) * 32);
              if (i % 3 == 0) wf0[g] = nv; else if (i % 3 == 1) wf1[g] = nv; else wf2[g] = nv;
            }
          }
#pragma unroll
          for (int g = 0; g < 4; ++g) acc[g] = mfma16(a0, cur[g], acc[g]);
        }
#pragma unroll
        for (int r = 0; r < 4; ++r) {
          float iv = acc[0][r] + ex[0][r], fv = acc[1][r] + ex[1][r];
          float gv = acc[2][r] + ex[2][r], ov = acc[3][r] + ex[3][r];
          float cn = sigf(fv) * cst[r] + sigf(iv) * tanh_(gv);
          cst[r] = cn;
          stage0[rb + r][lcol] = f2b(sigf(ov) * tanh_(cn));
        }
      }
    } else {
      if (k >= 1) {  // layer 1, step k-1
        bf16x8 wa0[4], wa1[4], wa2[4], wb0[4], wb1[4], wb2[4];
#pragma unroll
        for (int g = 0; g < 4; ++g) {
          wa0[g] = ld8(wp[g]);       wb0[g] = ld8(wp[4 + g]);
          wa1[g] = ld8(wp[g] + 32);  wb1[g] = ld8(wp[4 + g] + 32);
          wa2[g] = ld8(wp[g] + 64);  wb2[g] = ld8(wp[4 + g] + 64);
        }
        f32x4 acc[4] = {};
#pragma unroll
        for (int i = 0; i < 16; ++i) {
          const int so = ((i * 32 + lk) * 2) ^ ((lr & 7) << 4);
          bf16x8 a0 = *(const bf16x8*)((const char*)h0s + lr * 1024 + so);
          bf16x8 a1 = *(const bf16x8*)((const char*)h1s + lr * 1024 + so);
          bf16x8 ca[4], cb[4];
#pragma unroll
          for (int g = 0; g < 4; ++g) {
            ca[g] = (i % 3 == 0) ? wa0[g] : (i % 3 == 1) ? wa1[g] : wa2[g];
            cb[g] = (i % 3 == 0) ? wb0[g] : (i % 3 == 1) ? wb1[g] : wb2[g];
          }
          if (i + 3 < 16) {
#pragma unroll
            for (int g = 0; g < 4; ++g) {
              bf16x8 na = ld8(wp[g] + (i + 3) * 32);
              bf16x8 nb = ld8(wp[4 + g] + (i + 3) * 32);
              if (i % 3 == 0) { wa0[g] = na; wb0[g] = nb; }
              else if (i % 3 == 1) { wa1[g] = na; wb1[g] = nb; }
              else { wa2[g] = na; wb2[g] = nb; }
            }
          }
#pragma unroll
          for (int g = 0; g < 4; ++g) {
            acc[g] = mfma16(a0, ca[g], acc[g]);
            acc[g] = mfma16(a1, cb[g], acc[g]);
          }
        }
#pragma unroll
        for (int r = 0; r < 4; ++r) {
          float cn = sigf(acc[1][r]) * cst[r] + sigf(acc[0][r]) * tanh_(acc[2][r]);
          cst[r] = cn;
          stage1[rb + r][lcol] = f2b(sigf(acc[3][r]) * tanh_(cn));
        }
      }
    }
    __syncthreads();

    // ---- Phase C: cooperative write-out via sc0/sc1 ----
    if (tid < 256) {
      if (tid < 128) {
        if (k < T_) {
          const int lrow = tid >> 3, c8 = (tid & 7) * 8;
          i32x4 d = *(const i32x4*)&stage0[lrow][c8];
          u16* gp = h0buf + (size_t)(k + 1) * BH + (size_t)(bm * 16 + lrow) * H_ + bj * 64 + c8;
          asm volatile("global_store_dwordx4 %0, %1, off sc0 sc1" :: "v"(gp), "v"(d) : "memory");
        }
      } else {
        if (k >= 1) {
          const int t2 = tid - 128;
          const int lrow = t2 >> 3, c8 = (t2 & 7) * 8;
          i32x4 d = *(const i32x4*)&stage1[lrow][c8];
          u16* gp = h1buf + (size_t)k * BH + (size_t)(bm * 16 + lrow) * H_ + bj * 64 + c8;
          asm volatile("global_store_dwordx4 %0, %1, off sc0 sc1" :: "v"(gp), "v"(d) : "memory");
        }
      }
    }
    asm volatile("s_waitcnt vmcnt(0)" ::: "memory");
    __syncthreads();
    if (wv == 0) {
      const unsigned tgt = (unsigned)(k + 1);
      if (lane == 0)
        __hip_atomic_store(&gflags[bj], tgt, __ATOMIC_RELAXED, __HIP_MEMORY_SCOPE_AGENT);
      for (;;) {
        unsigned v = __hip_atomic_load(&gflags[lane & 7], __ATOMIC_RELAXED, __HIP_MEMORY_SCOPE_AGENT);
        if (__all(v >= tgt)) break;
        __builtin_amdgcn_s_sleep(1);
      }
    }
    __syncthreads();
    asm volatile("" ::: "memory");
  }
}

// ---------------- fused tail: feat1/pf1 in LDS -> feat2 -> softmax -> param head ----------------
// Saves the 128MB feat1/pf1 HBM round trip + one launch. LDS: f1s 64KB + pfs 64KB
// (trans[64][104] f32 overlays f1s after feat2's MFMA reads complete). 1 block/CU.
__global__ __launch_bounds__(256) void k_tail(
    const u16* __restrict__ outs,
    const u16* __restrict__ l1w, const float* __restrict__ l1b,
    const u16* __restrict__ r1w, const float* __restrict__ r1b,
    const u16* __restrict__ l2w, const float* __restrict__ l2b,
    const float* __restrict__ r2w, const float* __restrict__ r2b,
    const int* __restrict__ y,
    float* __restrict__ pgm, float* __restrict__ par) {
  __shared__ u16 f1s[64 * 512];   // feat1 (swizzled); later overlaid by trans (f32[64][104])
  __shared__ u16 pfs[64 * 512];   // pf1 (swizzled)
  const int lane = threadIdx.x & 63;
  const int wv = threadIdx.x >> 6;        // 0..3, each owns 16 rows
  const int lr = lane & 15;
  const int lk = (lane >> 4) * 8;
  const int rb = (lane >> 4) * 4;
  const int lrow0 = wv * 16;
  const int ar = blockIdx.x * 64 + lrow0 + lr;

  // A fragments (outs rows), reused for both GEMMs
  bf16x8 a[16];
  {
    const u16* ap = outs + (size_t)ar * H_ + lk;
#pragma unroll
    for (int i = 0; i < 16; ++i) a[i] = ld8(ap + i * 32);
  }

  // GEMM1 -> f1s, GEMM2 -> pfs (depth-1 weight prefetch), bf16 in swizzled LDS
  for (int w = 0; w < 2; ++w) {
    const u16* W = w ? r1w : l1w;
    const float* bias = w ? r1b : l1b;
    u16* dst = w ? pfs : f1s;
    for (int nc = 0; nc < 4; ++nc) {
      const u16* wr[8];
#pragma unroll
      for (int n = 0; n < 8; ++n)
        wr[n] = W + (size_t)(nc * 128 + n * 16 + lr) * H_ + lk;
      bf16x8 wcur[8];
#pragma unroll
      for (int n = 0; n < 8; ++n) wcur[n] = ld8(wr[n]);
      f32x4 acc[8] = {};
#pragma unroll
      for (int i = 0; i < 16; ++i) {
        bf16x8 wnext[8];
        if (i < 15) {
#pragma unroll
          for (int n = 0; n < 8; ++n) wnext[n] = ld8(wr[n] + (i + 1) * 32);
        }
#pragma unroll
        for (int n = 0; n < 8; ++n) acc[n] = mfma16(a[i], wcur[n], acc[n]);
        if (i < 15) {
#pragma unroll
          for (int n = 0; n < 8; ++n) wcur[n] = wnext[n];
        }
      }
#pragma unroll
      for (int n = 0; n < 8; ++n) {
        const int colc = nc * 128 + n * 16 + lr;
        const float bv = bias[colc];
#pragma unroll
        for (int r = 0; r < 4; ++r) {
          const int row = lrow0 + rb + r;
          *(u16*)((char*)dst + row * 1024 + ((colc * 2) ^ ((row & 7) << 4))) =
              f2b(fmaxf(acc[n][r] + bv, 0.f));
        }
      }
    }
  }
  __syncthreads();

  // feat2 = feat1 @ l2w^T + l2b  (feat1 from swizzled LDS)
  f32x4 acc2[7] = {};
  {
    const int arow = lrow0 + lr;
#pragma unroll
    for (int i = 0; i < 16; ++i) {
      bf16x8 av = *(const bf16x8*)((const char*)f1s + arow * 1024 +
                                   (((i * 32 + lk) * 2) ^ ((arow & 7) << 4)));
#pragma unroll
      for (int c = 0; c < 7; ++c) {
        const int n = c * 16 + lr;
        bf16x8 b = {};
        if (n < V1_) b = ld8(l2w + (size_t)n * H_ + i * 32 + lk);
        acc2[c] = mfma16(av, b, acc2[c]);
      }
    }
  }
  __syncthreads();   // f1s reads complete -> safe to overlay trans
  float* trans = (float*)f1s;  // [64][104]

  // softmax epilogue: log_softmax -> pgm (global), softmax -> trans (LDS)
#pragma unroll
  for (int r = 0; r < 4; ++r) {
    float v[7];
    float mx = -1e30f;
#pragma unroll
    for (int c = 0; c < 7; ++c) {
      const int colc = c * 16 + lr;
      v[c] = (colc < V1_) ? acc2[c][r] + l2b[colc] : -1e30f;
      mx = fmaxf(mx, v[c]);
    }
#pragma unroll
    for (int o = 1; o < 16; o <<= 1) mx = fmaxf(mx, __shfl_xor(mx, o, 64));
    float e[7], s = 0.f;
#pragma unroll
    for (int c = 0; c < 7; ++c) { e[c] = (c * 16 + lr < V1_) ? __expf(v[c] - mx) : 0.f; s += e[c]; }
#pragma unroll
    for (int o = 1; o < 16; o <<= 1) s += __shfl_xor(s, o, 64);
    const float lz = __logf(s), inv = 1.f / s;
    const int lrow = lrow0 + rb + r;
    const int m = blockIdx.x * 64 + lrow;
    const int t = m >> 9, bb = m & 511;
    float* po = pgm + ((size_t)bb * T_ + t) * V1_;
#pragma unroll
    for (int c = 0; c < 7; ++c) {
      const int colc = c * 16 + lr;
      if (colc < V1_) { po[colc] = v[c] - mx - lz; trans[lrow * 104 + colc] = e[c] * inv; }
    }
  }
  __syncthreads();

  // param head: concat(trans, pf1) . r2w[idx*8+p] + r2b ; pf1 from swizzled LDS
  for (int rr = 0; rr < 16; ++rr) {
    const int lrow = wv * 16 + rr;
    const int m = blockIdx.x * 64 + lrow;
    const int t = m >> 9, bb = m & 511;
    const int idx = y[bb * T_ + t];
    const float* wb = r2w + (size_t)idx * P_ * 613;
    float a8[P_] = {};
    for (int kk = lane; kk < 613; kk += 64) {
      float xv;
      if (kk < V1_) xv = trans[lrow * 104 + kk];
      else {
        const int cc = kk - V1_;
        xv = b2f(*(const u16*)((const char*)pfs + lrow * 1024 + ((cc * 2) ^ ((lrow & 7) << 4))));
      }
#pragma unroll
      for (int p = 0; p < P_; ++p) a8[p] += xv * wb[(size_t)p * 613 + kk];
    }
#pragma unroll
    for (int p = 0; p < P_; ++p)
#pragma unroll
      for (int o = 1; o < 64; o <<= 1) a8[p] += __shfl_xor(a8[p], o, 64);
    if (lane < P_) par[((size_t)bb * T_ + t) * P_ + lane] = a8[lane] + r2b[idx * P_ + lane];
  }
}

extern "C" void kernel_launch(void* const* d_in, const int* in_sizes, int n_in,
                              void* d_out, int out_size, void* d_ws, size_t ws_size,
                              hipStream_t stream) {
  (void)in_sizes; (void)n_in; (void)out_size; (void)ws_size;
  const float* x     = (const float*)d_in[0];
  const int*   y     = (const int*)d_in[1];
  const float* embed = (const float*)d_in[2];
  const float* wih0  = (const float*)d_in[3];
  const float* whh0  = (const float*)d_in[4];
  const float* wih1  = (const float*)d_in[5];
  const float* whh1  = (const float*)d_in[6];
  const float* l1w   = (const float*)d_in[7];
  const float* l1b   = (const float*)d_in[8];
  const float* l2w   = (const float*)d_in[9];
  const float* l2b   = (const float*)d_in[10];
  const float* r1w   = (const float*)d_in[11];
  const float* r1b   = (const float*)d_in[12];
  const float* r2w   = (const float*)d_in[13];
  const float* r2b   = (const float*)d_in[14];

  float* out_pgm = (float*)d_out;
  float* out_par = out_pgm + (size_t)B_ * T_ * V1_;

  char* ws = (char*)d_ws;
  size_t off = 0;
  auto alloc = [&](size_t bytes) { void* p = ws + off; off += (bytes + 255) & ~(size_t)255; return p; };

  const size_t BH2 = (size_t)B_ * H_ * 2;  // one slot, bytes (512 KB)

  // [flags | h0buf slot0..] contiguous -> first memset covers flags + h0 slot 0
  unsigned* flags = (unsigned*)alloc(32 * 16 * 4);         // 2 KB
  u16* h0buf  = (u16*)alloc((size_t)(T_ + 1) * BH2);       // 65 write-once slots
  u16* h1buf  = (u16*)alloc((size_t)(T_ + 1) * BH2);       // 65 write-once slots (slots 1..64 = outs)

  float* EX0   = (float*)alloc((size_t)EXR * G4_ * 4);
  u16* ex_src  = (u16*)alloc((size_t)EXR * IN_ * 2);
  u16* wih0b   = (u16*)alloc((size_t)4 * H_ * IN_ * 2);
  u16* whh0b   = (u16*)alloc((size_t)4 * H_ * H_ * 2);
  u16* wih1b   = (u16*)alloc((size_t)4 * H_ * H_ * 2);
  u16* whh1b   = (u16*)alloc((size_t)4 * H_ * H_ * 2);
  u16* l1wb    = (u16*)alloc((size_t)H_ * H_ * 2);
  u16* r1wb    = (u16*)alloc((size_t)H_ * H_ * 2);
  u16* l2wb    = (u16*)alloc((size_t)V1_ * H_ * 2);

  (void)hipMemsetAsync(flags, 0, 32 * 16 * 4 + BH2, stream);  // flags + h0buf slot 0
  (void)hipMemsetAsync(h1buf, 0, BH2, stream);                // h1buf slot 0

  CvtArgs ca;
  const float* srcs[9] = {embed, x, wih0, whh0, wih1, whh1, l1w, r1w, l2w};
  u16* dsts[9] = {ex_src, ex_src + (size_t)V1_ * IN_, wih0b, whh0b, wih1b, whh1b, l1wb, r1wb, l2wb};
  int ns[9] = {V1_ * IN_, B_ * IN_, 4 * H_ * IN_, 4 * H_ * H_, 4 * H_ * H_, 4 * H_ * H_,
               H_ * H_, H_ * H_, V1_ * H_};
  int acc4 = 0;
  for (int i = 0; i < 9; ++i) {
    ca.src[i] = srcs[i]; ca.dst[i] = dsts[i]; ca.pre[i] = acc4; acc4 += ns[i] / 4;
  }
  ca.pre[9] = acc4;
  k_cvtall<<<(acc4 + 255) / 256, 256, 0, stream>>>(ca);

  k_precomp<<<dim3(10, 32), 256, 0, stream>>>(ex_src, wih0b, EX0);

  k_scan<<<NBLK, 512, 0, stream>>>(whh0b, wih1b, whh1b, EX0, y, h0buf, h1buf, flags);

  u16* outs = h1buf + (size_t)B_ * H_;  // slots 1..64 = h1 after steps 0..63 = outs[T][B][H]
  k_tail<<<512, 256, 0, stream>>>(outs, l1wb, l1b, r1wb, r1b, l2wb, l2b, r2w, r2b, y,
                                  out_pgm, out_par);
}

// Round 21
// 1932.743 us; speedup vs baseline: 1.0350x; 1.0350x over previous
//
#include <hip/hip_runtime.h>
#include <stdint.h>

typedef unsigned short u16;
typedef short bf16x8 __attribute__((ext_vector_type(8)));
typedef float f32x4 __attribute__((ext_vector_type(4)));
typedef int i32x4 __attribute__((ext_vector_type(4)));

#define DEV static __device__ __forceinline__

constexpr int B_ = 512, T_ = 64, IN_ = 256, H_ = 512, V1_ = 101, P_ = 8, G4_ = 2048;
constexpr int EXR = 613;      // 101 embed rows + 512 x rows
constexpr int M_  = T_ * B_;  // 32768
constexpr int NBLK = 256;     // scan grid: 32 bm x 8 bj; bj == XCD (round-robin %8)

DEV float b2f(u16 u) { union { uint32_t i; float f; } v; v.i = ((uint32_t)u) << 16; return v.f; }
DEV u16 f2b(float f) {
  union { float f; uint32_t i; } v; v.f = f;
  uint32_t i = v.i;
  return (u16)((i + 0x7fffu + ((i >> 16) & 1u)) >> 16);  // RNE
}
DEV float sigf(float x) { return 1.f / (1.f + __expf(-x)); }
DEV float tanh_(float x) {
  float c = fminf(fmaxf(x, -15.f), 15.f);
  float e = __expf(2.f * c);
  return (e - 1.f) / (e + 1.f);
}
DEV bf16x8 ld8(const u16* p) { return *reinterpret_cast<const bf16x8*>(p); }
DEV f32x4 mfma16(bf16x8 a, bf16x8 b, f32x4 c) {
  return __builtin_amdgcn_mfma_f32_16x16x32_bf16(a, b, c, 0, 0, 0);
}

// ---------------- fused f32 -> bf16 conversion over 9 segments ----------------
struct CvtArgs {
  const float* src[9];
  u16* dst[9];
  int pre[10];  // prefix sums in float4 units
};

__global__ __launch_bounds__(256) void k_cvtall(CvtArgs a) {
  int gid = blockIdx.x * 256 + threadIdx.x;
  if (gid >= a.pre[9]) return;
  int s = 0;
#pragma unroll
  for (int i = 1; i < 9; ++i) s += (gid >= a.pre[i]);
  const int local = gid - a.pre[s];
  const float4 v = reinterpret_cast<const float4*>(a.src[s])[local];
  ushort4 o;
  o.x = f2b(v.x); o.y = f2b(v.y); o.z = f2b(v.z); o.w = f2b(v.w);
  reinterpret_cast<ushort4*>(a.dst[s])[local] = o;
}

// ---------------- EX0 = [embed; x] @ w_ih0^T   (613 x 2048) f32 ----------------
__global__ __launch_bounds__(256) void k_precomp(const u16* __restrict__ ex_src,
                                                 const u16* __restrict__ wih0b,
                                                 float* __restrict__ EX0) {
  const int lane = threadIdx.x & 63;
  const int wv = threadIdx.x >> 6;
  const int m0 = blockIdx.x * 64 + wv * 16;
  const int n0 = blockIdx.y * 64;
  const int lr = lane & 15;
  const int lk = (lane >> 4) * 8;

  const int arow = m0 + lr;
  const bool valid = arow < EXR;

  f32x4 acc[4] = {};
  for (int k0 = 0; k0 < IN_; k0 += 32) {
    bf16x8 a = {};
    if (valid) a = ld8(ex_src + (size_t)arow * IN_ + k0 + lk);
#pragma unroll
    for (int c = 0; c < 4; ++c) {
      bf16x8 b = ld8(wih0b + (size_t)(n0 + c * 16 + lr) * IN_ + k0 + lk);
      acc[c] = mfma16(a, b, acc[c]);
    }
  }
  const int rb = (lane >> 4) * 4;
#pragma unroll
  for (int c = 0; c < 4; ++c)
#pragma unroll
    for (int r = 0; r < 4; ++r) {
      int row = m0 + rb + r;
      int col = n0 + c * 16 + (lane & 15);
      if (row < EXR) EX0[(size_t)row * G4_ + col] = acc[c][r];
    }
}

// ---------------- persistent 2-layer LSTM scan (r18 champion) ----------------
// 256 blocks x 512 thr; waves 0-3 = layer0, waves 4-7 = layer1; h tiles staged once into
// swizzled LDS; write-once h slot buffers (plain cached reads); sc0/sc1 write-through
// stores; per-bm-group flag sync; depth-3 rolling weight prefetch; EX0 gather hoisted.
__global__ __launch_bounds__(512, 1) void k_scan(
    const u16* __restrict__ whh0, const u16* __restrict__ wih1, const u16* __restrict__ whh1,
    const float* __restrict__ EX0, const int* __restrict__ y,
    u16* h0buf, u16* h1buf, unsigned* flags /* [32][16] u32, pre-zeroed */) {
  __shared__ u16 h0s[16 * 512];   // swizzled
  __shared__ u16 h1s[16 * 512];   // swizzled (L1 only)
  __shared__ u16 stage0[16][64];
  __shared__ u16 stage1[16][64];
  const size_t BH = (size_t)B_ * H_;
  const int tid = threadIdx.x;
  const int lane = tid & 63;
  const int wv = tid >> 6;           // 0..3: layer0 quarter; 4..7: layer1 quarter
  const int q = wv & 3;              // col quarter
  const bool isL1 = wv >= 4;
  const int bm = blockIdx.x >> 3;    // 0..31 batch tile (16 rows)
  const int bj = blockIdx.x & 7;     // 0..7 h-col tile (64 cols) == XCD
  const int lr = lane & 15;
  const int lk = (lane >> 4) * 8;    // k-offset within 32-wide K step
  const int col = bj * 64 + q * 16 + lr;
  const int rb = (lane >> 4) * 4;
  const int lcol = q * 16 + lr;

  const u16* wp[8];  // L0: wp[g]=whh0 ; L1: wp[g]=wih1, wp[4+g]=whh1
#pragma unroll
  for (int g = 0; g < 4; ++g) {
    if (!isL1) {
      wp[g] = whh0 + (size_t)(g * H_ + col) * H_ + lk;
      wp[4 + g] = whh0 + (size_t)(g * H_ + col) * H_ + lk;  // unused, keep defined
    } else {
      wp[g] = wih1 + (size_t)(g * H_ + col) * H_ + lk;
      wp[4 + g] = whh1 + (size_t)(g * H_ + col) * H_ + lk;
    }
  }
  f32x4 cst = {};  // c0 for L0 waves, c1 for L1 waves
  unsigned* gflags = flags + bm * 16;

  for (int k = 0; k <= T_; ++k) {
    // ---- Phase A: cooperative staging of h tiles into swizzled LDS ----
    {
      const u16* h0g = h0buf + (size_t)k * BH + (size_t)(bm * 16) * H_;
#pragma unroll
      for (int rr = 0; rr < 2; ++rr) {
        const int idx = rr * 512 + tid;          // 1024 chunks of 16B
        const int row = idx >> 6, cc = idx & 63;
        i32x4 d = *(const i32x4*)(h0g + (size_t)row * H_ + cc * 8);
        *(i32x4*)((char*)h0s + row * 1024 + ((cc * 16) ^ ((row & 7) << 4))) = d;
      }
      if (k >= 1) {
        const u16* h1g = h1buf + (size_t)(k - 1) * BH + (size_t)(bm * 16) * H_;
#pragma unroll
        for (int rr = 0; rr < 2; ++rr) {
          const int idx = rr * 512 + tid;
          const int row = idx >> 6, cc = idx & 63;
          i32x4 d = *(const i32x4*)(h1g + (size_t)row * H_ + cc * 8);
          *(i32x4*)((char*)h1s + row * 1024 + ((cc * 16) ^ ((row & 7) << 4))) = d;
        }
      }
    }
    __syncthreads();

    // ---- Phase B: compute (depth-3 rolling weight prefetch) ----
    if (!isL1) {
      if (k < T_) {  // layer 0, step k
        float ex[4][4];
#pragma unroll
        for (int r = 0; r < 4; ++r) {
          const int row = bm * 16 + rb + r;
          const int srow = (k == 0) ? (V1_ + row) : y[row * T_ + k - 1];
          const float* bp = EX0 + (size_t)srow * G4_ + col;
#pragma unroll
          for (int g = 0; g < 4; ++g) ex[g][r] = bp[(size_t)g * H_];
        }
        bf16x8 wf0[4], wf1[4], wf2[4];
#pragma unroll
        for (int g = 0; g < 4; ++g) {
          wf0[g] = ld8(wp[g]);
          wf1[g] = ld8(wp[g] + 32);
          wf2[g] = ld8(wp[g] + 64);
        }
        f32x4 acc[4] = {};
#pragma unroll
        for (int i = 0; i < 16; ++i) {
          bf16x8 a0 = *(const bf16x8*)((const char*)h0s + lr * 1024 + (((i * 32 + lk) * 2) ^ ((lr & 7) << 4)));
          bf16x8 cur[4];
#pragma unroll
          for (int g = 0; g < 4; ++g)
            cur[g] = (i % 3 == 0) ? wf0[g] : (i % 3 == 1) ? wf1[g] : wf2[g];
          if (i + 3 < 16) {
#pragma unroll
            for (int g = 0; g < 4; ++g) {
              bf16x8 nv = ld8(wp[g] + (i + 3) * 32);
              if (i % 3 == 0) wf0[g] = nv; else if (i % 3 == 1) wf1[g] = nv; else wf2[g] = nv;
            }
          }
#pragma unroll
          for (int g = 0; g < 4; ++g) acc[g] = mfma16(a0, cur[g], acc[g]);
        }
#pragma unroll
        for (int r = 0; r < 4; ++r) {
          float iv = acc[0][r] + ex[0][r], fv = acc[1][r] + ex[1][r];
          float gv = acc[2][r] + ex[2][r], ov = acc[3][r] + ex[3][r];
          float cn = sigf(fv) * cst[r] + sigf(iv) * tanh_(gv);
          cst[r] = cn;
          stage0[rb + r][lcol] = f2b(sigf(ov) * tanh_(cn));
        }
      }
    } else {
      if (k >= 1) {  // layer 1, step k-1
        bf16x8 wa0[4], wa1[4], wa2[4], wb0[4], wb1[4], wb2[4];
#pragma unroll
        for (int g = 0; g < 4; ++g) {
          wa0[g] = ld8(wp[g]);       wb0[g] = ld8(wp[4 + g]);
          wa1[g] = ld8(wp[g] + 32);  wb1[g] = ld8(wp[4 + g] + 32);
          wa2[g] = ld8(wp[g] + 64);  wb2[g] = ld8(wp[4 + g] + 64);
        }
        f32x4 acc[4] = {};
#pragma unroll
        for (int i = 0; i < 16; ++i) {
          const int so = ((i * 32 + lk) * 2) ^ ((lr & 7) << 4);
          bf16x8 a0 = *(const bf16x8*)((const char*)h0s + lr * 1024 + so);
          bf16x8 a1 = *(const bf16x8*)((const char*)h1s + lr * 1024 + so);
          bf16x8 ca[4], cb[4];
#pragma unroll
          for (int g = 0; g < 4; ++g) {
            ca[g] = (i % 3 == 0) ? wa0[g] : (i % 3 == 1) ? wa1[g] : wa2[g];
            cb[g] = (i % 3 == 0) ? wb0[g] : (i % 3 == 1) ? wb1[g] : wb2[g];
          }
          if (i + 3 < 16) {
#pragma unroll
            for (int g = 0; g < 4; ++g) {
              bf16x8 na = ld8(wp[g] + (i + 3) * 32);
              bf16x8 nb = ld8(wp[4 + g] + (i + 3) * 32);
              if (i % 3 == 0) { wa0[g] = na; wb0[g] = nb; }
              else if (i % 3 == 1) { wa1[g] = na; wb1[g] = nb; }
              else { wa2[g] = na; wb2[g] = nb; }
            }
          }
#pragma unroll
          for (int g = 0; g < 4; ++g) {
            acc[g] = mfma16(a0, ca[g], acc[g]);
            acc[g] = mfma16(a1, cb[g], acc[g]);
          }
        }
#pragma unroll
        for (int r = 0; r < 4; ++r) {
          float cn = sigf(acc[1][r]) * cst[r] + sigf(acc[0][r]) * tanh_(acc[2][r]);
          cst[r] = cn;
          stage1[rb + r][lcol] = f2b(sigf(acc[3][r]) * tanh_(cn));
        }
      }
    }
    __syncthreads();

    // ---- Phase C: cooperative write-out via sc0/sc1 (write-through to coherence point) ----
    if (tid < 256) {
      if (tid < 128) {
        if (k < T_) {
          const int lrow = tid >> 3, c8 = (tid & 7) * 8;
          i32x4 d = *(const i32x4*)&stage0[lrow][c8];
          u16* gp = h0buf + (size_t)(k + 1) * BH + (size_t)(bm * 16 + lrow) * H_ + bj * 64 + c8;
          asm volatile("global_store_dwordx4 %0, %1, off sc0 sc1" :: "v"(gp), "v"(d) : "memory");
        }
      } else {
        if (k >= 1) {
          const int t2 = tid - 128;
          const int lrow = t2 >> 3, c8 = (t2 & 7) * 8;
          i32x4 d = *(const i32x4*)&stage1[lrow][c8];
          u16* gp = h1buf + (size_t)k * BH + (size_t)(bm * 16 + lrow) * H_ + bj * 64 + c8;
          asm volatile("global_store_dwordx4 %0, %1, off sc0 sc1" :: "v"(gp), "v"(d) : "memory");
        }
      }
    }
    asm volatile("s_waitcnt vmcnt(0)" ::: "memory");  // sc stores ack'd at coherence point
    __syncthreads();
    // group sync: arrive = store own flag; wait = wave0 polls the group's 8 flags
    if (wv == 0) {
      const unsigned tgt = (unsigned)(k + 1);
      if (lane == 0)
        __hip_atomic_store(&gflags[bj], tgt, __ATOMIC_RELAXED, __HIP_MEMORY_SCOPE_AGENT);
      for (;;) {
        unsigned v = __hip_atomic_load(&gflags[lane & 7], __ATOMIC_RELAXED, __HIP_MEMORY_SCOPE_AGENT);
        if (__all(v >= tgt)) break;
        __builtin_amdgcn_s_sleep(1);
      }
    }
    __syncthreads();
    asm volatile("" ::: "memory");
  }
}

// ---------------- feat1 = relu(outs@l1w^T+l1b), pf1 = relu(outs@r1w^T+r1b) ----------------
// depth-1 prefetch of the 8 weight fragments per K-iteration.
__global__ __launch_bounds__(256) void k_fused1(const u16* __restrict__ outs,
                                                const u16* __restrict__ l1w, const float* __restrict__ l1b,
                                                const u16* __restrict__ r1w, const float* __restrict__ r1b,
                                                u16* __restrict__ feat1, u16* __restrict__ pf1) {
  const int lane = threadIdx.x & 63;
  const int wv = threadIdx.x >> 6;
  const int lr = lane & 15;
  const int lk = (lane >> 4) * 8;
  const int ar = blockIdx.x * 64 + wv * 16 + lr;
  const int rb = (lane >> 4) * 4;
  const int row0 = blockIdx.x * 64 + wv * 16 + rb;

  bf16x8 a[16];
  {
    const u16* ap = outs + (size_t)ar * H_ + lk;
#pragma unroll
    for (int i = 0; i < 16; ++i) a[i] = ld8(ap + i * 32);
  }
  for (int w = 0; w < 2; ++w) {
    const u16* W = w ? r1w : l1w;
    const float* bias = w ? r1b : l1b;
    u16* dst = w ? pf1 : feat1;
    for (int nc = 0; nc < 4; ++nc) {
      const u16* wr[8];
#pragma unroll
      for (int n = 0; n < 8; ++n)
        wr[n] = W + (size_t)(nc * 128 + n * 16 + lr) * H_ + lk;
      bf16x8 wcur[8];
#pragma unroll
      for (int n = 0; n < 8; ++n) wcur[n] = ld8(wr[n]);
      f32x4 acc[8] = {};
#pragma unroll
      for (int i = 0; i < 16; ++i) {
        bf16x8 wnext[8];
        if (i < 15) {
#pragma unroll
          for (int n = 0; n < 8; ++n) wnext[n] = ld8(wr[n] + (i + 1) * 32);
        }
#pragma unroll
        for (int n = 0; n < 8; ++n) acc[n] = mfma16(a[i], wcur[n], acc[n]);
        if (i < 15) {
#pragma unroll
          for (int n = 0; n < 8; ++n) wcur[n] = wnext[n];
        }
      }
#pragma unroll
      for (int n = 0; n < 8; ++n) {
        const int colc = nc * 128 + n * 16 + lr;
        const float bv = bias[colc];
#pragma unroll
        for (int r = 0; r < 4; ++r)
          dst[(size_t)(row0 + r) * H_ + colc] = f2b(fmaxf(acc[n][r] + bv, 0.f));
      }
    }
  }
}

// ---------------- feat2 + log_softmax (pgm out) + softmax + param head ----------------
__global__ __launch_bounds__(256) void k_fused2(const u16* __restrict__ feat1,
                                                const u16* __restrict__ l2w, const float* __restrict__ l2b,
                                                const u16* __restrict__ pf1,
                                                const float* __restrict__ r2w, const float* __restrict__ r2b,
                                                const int* __restrict__ y,
                                                float* __restrict__ pgm, float* __restrict__ par) {
  __shared__ float trans[64][104];
  const int lane = threadIdx.x & 63;
  const int wv = threadIdx.x >> 6;
  const int lr = lane & 15;
  const int lk = (lane >> 4) * 8;
  const int ar = blockIdx.x * 64 + wv * 16 + lr;
  const int rb = (lane >> 4) * 4;

  f32x4 acc[7] = {};
  {
    const u16* ap = feat1 + (size_t)ar * H_ + lk;
#pragma unroll
    for (int i = 0; i < 16; ++i) {
      bf16x8 av = ld8(ap + i * 32);
#pragma unroll
      for (int c = 0; c < 7; ++c) {
        const int n = c * 16 + lr;
        bf16x8 b = {};
        if (n < V1_) b = ld8(l2w + (size_t)n * H_ + i * 32 + lk);
        acc[c] = mfma16(av, b, acc[c]);
      }
    }
  }
#pragma unroll
  for (int r = 0; r < 4; ++r) {
    float v[7];
    float mx = -1e30f;
#pragma unroll
    for (int c = 0; c < 7; ++c) {
      const int colc = c * 16 + lr;
      v[c] = (colc < V1_) ? acc[c][r] + l2b[colc] : -1e30f;
      mx = fmaxf(mx, v[c]);
    }
#pragma unroll
    for (int o = 1; o < 16; o <<= 1) mx = fmaxf(mx, __shfl_xor(mx, o, 64));
    float e[7], s = 0.f;
#pragma unroll
    for (int c = 0; c < 7; ++c) { e[c] = (c * 16 + lr < V1_) ? __expf(v[c] - mx) : 0.f; s += e[c]; }
#pragma unroll
    for (int o = 1; o < 16; o <<= 1) s += __shfl_xor(s, o, 64);
    const float lz = __logf(s), inv = 1.f / s;
    const int m = blockIdx.x * 64 + wv * 16 + rb + r;
    const int t = m >> 9, bb = m & 511;
    float* po = pgm + ((size_t)bb * T_ + t) * V1_;
#pragma unroll
    for (int c = 0; c < 7; ++c) {
      const int colc = c * 16 + lr;
      if (colc < V1_) { po[colc] = v[c] - mx - lz; trans[wv * 16 + rb + r][colc] = e[c] * inv; }
    }
  }
  __syncthreads();
  for (int rr = 0; rr < 16; ++rr) {
    const int m = blockIdx.x * 64 + wv * 16 + rr;
    const int t = m >> 9, bb = m & 511;
    const int idx = y[bb * T_ + t];
    const float* wb = r2w + (size_t)idx * P_ * 613;
    float a8[P_] = {};
    for (int kk = lane; kk < 613; kk += 64) {
      float xv = (kk < V1_) ? trans[wv * 16 + rr][kk] : b2f(pf1[(size_t)m * H_ + kk - V1_]);
#pragma unroll
      for (int p = 0; p < P_; ++p) a8[p] += xv * wb[(size_t)p * 613 + kk];
    }
#pragma unroll
    for (int p = 0; p < P_; ++p)
#pragma unroll
      for (int o = 1; o < 64; o <<= 1) a8[p] += __shfl_xor(a8[p], o, 64);
    if (lane < P_) par[((size_t)bb * T_ + t) * P_ + lane] = a8[lane] + r2b[idx * P_ + lane];
  }
}

extern "C" void kernel_launch(void* const* d_in, const int* in_sizes, int n_in,
                              void* d_out, int out_size, void* d_ws, size_t ws_size,
                              hipStream_t stream) {
  (void)in_sizes; (void)n_in; (void)out_size; (void)ws_size;
  const float* x     = (const float*)d_in[0];
  const int*   y     = (const int*)d_in[1];
  const float* embed = (const float*)d_in[2];
  const float* wih0  = (const float*)d_in[3];
  const float* whh0  = (const float*)d_in[4];
  const float* wih1  = (const float*)d_in[5];
  const float* whh1  = (const float*)d_in[6];
  const float* l1w   = (const float*)d_in[7];
  const float* l1b   = (const float*)d_in[8];
  const float* l2w   = (const float*)d_in[9];
  const float* l2b   = (const float*)d_in[10];
  const float* r1w   = (const float*)d_in[11];
  const float* r1b   = (const float*)d_in[12];
  const float* r2w   = (const float*)d_in[13];
  const float* r2b   = (const float*)d_in[14];

  float* out_pgm = (float*)d_out;
  float* out_par = out_pgm + (size_t)B_ * T_ * V1_;

  char* ws = (char*)d_ws;
  size_t off = 0;
  auto alloc = [&](size_t bytes) { void* p = ws + off; off += (bytes + 255) & ~(size_t)255; return p; };

  const size_t BH2 = (size_t)B_ * H_ * 2;  // one slot, bytes (512 KB)

  // [flags | h0buf slot0..] contiguous -> first memset covers flags + h0 slot 0
  unsigned* flags = (unsigned*)alloc(32 * 16 * 4);         // 2 KB
  u16* h0buf  = (u16*)alloc((size_t)(T_ + 1) * BH2);       // 65 write-once slots
  u16* h1buf  = (u16*)alloc((size_t)(T_ + 1) * BH2);       // 65 write-once slots (slots 1..64 = outs)

  float* EX0   = (float*)alloc((size_t)EXR * G4_ * 4);
  u16* ex_src  = (u16*)alloc((size_t)EXR * IN_ * 2);
  u16* wih0b   = (u16*)alloc((size_t)4 * H_ * IN_ * 2);
  u16* whh0b   = (u16*)alloc((size_t)4 * H_ * H_ * 2);
  u16* wih1b   = (u16*)alloc((size_t)4 * H_ * H_ * 2);
  u16* whh1b   = (u16*)alloc((size_t)4 * H_ * H_ * 2);
  u16* l1wb    = (u16*)alloc((size_t)H_ * H_ * 2);
  u16* r1wb    = (u16*)alloc((size_t)H_ * H_ * 2);
  u16* l2wb    = (u16*)alloc((size_t)V1_ * H_ * 2);
  u16* feat1   = (u16*)alloc((size_t)M_ * H_ * 2);
  u16* pf1     = (u16*)alloc((size_t)M_ * H_ * 2);

  (void)hipMemsetAsync(flags, 0, 32 * 16 * 4 + BH2, stream);  // flags + h0buf slot 0
  (void)hipMemsetAsync(h1buf, 0, BH2, stream);                // h1buf slot 0

  CvtArgs ca;
  const float* srcs[9] = {embed, x, wih0, whh0, wih1, whh1, l1w, r1w, l2w};
  u16* dsts[9] = {ex_src, ex_src + (size_t)V1_ * IN_, wih0b, whh0b, wih1b, whh1b, l1wb, r1wb, l2wb};
  int ns[9] = {V1_ * IN_, B_ * IN_, 4 * H_ * IN_, 4 * H_ * H_, 4 * H_ * H_, 4 * H_ * H_,
               H_ * H_, H_ * H_, V1_ * H_};
  int acc4 = 0;
  for (int i = 0; i < 9; ++i) {
    ca.src[i] = srcs[i]; ca.dst[i] = dsts[i]; ca.pre[i] = acc4; acc4 += ns[i] / 4;
  }
  ca.pre[9] = acc4;
  k_cvtall<<<(acc4 + 255) / 256, 256, 0, stream>>>(ca);

  k_precomp<<<dim3(10, 32), 256, 0, stream>>>(ex_src, wih0b, EX0);

  k_scan<<<NBLK, 512, 0, stream>>>(whh0b, wih1b, whh1b, EX0, y, h0buf, h1buf, flags);

  u16* outs = h1buf + (size_t)B_ * H_;  // slots 1..64 = h1 after steps 0..63 = outs[T][B][H]
  k_fused1<<<512, 256, 0, stream>>>(outs, l1wb, l1b, r1wb, r1b, feat1, pf1);
  k_fused2<<<512, 256, 0, stream>>>(feat1, l2wb, l2b, pf1, r2w, r2b, y, out_pgm, out_par);
}